// Round 4
// baseline (187.165 us; speedup 1.0000x reference)
//
#include <hip/hip_runtime.h>
#include <math.h>

#define BB 256
#define SSEQ 128
#define INPUT 256
#define PD 128
#define EE 64
#define RW 256
#define MM 512
#define WW 64
#define KD 384          // IN_DIM

typedef _Float16 half8 __attribute__((ext_vector_type(8)));
typedef __fp16 fp16x2 __attribute__((ext_vector_type(2)));
typedef float float4v __attribute__((ext_vector_type(4)));
typedef float f32x16 __attribute__((ext_vector_type(16)));
typedef unsigned int uint2v __attribute__((ext_vector_type(2)));

#define LOG2E 1.44269504088896f
#define OUT1 8388608u

// LDS byte layout (monolith + k1/k2 reuse the same offsets).
#define MEMT_OFF 65536
#define MEMT16   4096            // MEMT_OFF in uint4 units
#define F32_OFF  131072
#define LDS_BYTES_K1 (131072 + 6144)   // Wq image + f32 scratch
#define LDS_BYTES_K2 131072            // mem + memT images
#define UE_O 0
#define PE_O 64
#define QPE_O 192
#define QP_O 448                  // qpart [1024]

// workspace layout (diagnostic split): bqf u32 image + prebuilt f16 mem images
#define QG_OFF   0u               // 16 MB: [b][r][kc][jp][hh][s] u32
#define M16_OFF  (16u<<20)        // 1 MB: mem f16 [sid][m][w]
#define MT16_OFF (17u<<20)        // 1 MB: memT f16 [sid][w][m]
#define WS_NEED  (18u<<20)

#define QIDX(b,r,kc,jp,hh,s) ((((((size_t)(b)*4 + (r))*4 + (kc))*4 + (jp))*2 + (hh))*128 + (s))

union H8 { half8 h8; unsigned int u[4]; uint4 u4; };

__device__ __forceinline__ unsigned int pk2(float a, float b) {
    union { fp16x2 h; unsigned int u; } p;
    p.h = __builtin_amdgcn_cvt_pkrtz(a, b);
    return p.u;
}

// v_permlane32_swap_b32 via the builtin (NOT inline asm: two "+v" asm operands
// holding the same value can be coalesced into ONE physical VGPR -> self-swap
// garbage. That was R1's absmax=4.6e7 failure.)
// returns r[0] = [a_lo | b_lo], r[1] = [a_hi | b_hi]
__device__ __forceinline__ float xhalf_max(float v) {
    uint2v r = __builtin_amdgcn_permlane32_swap(__float_as_uint(v), __float_as_uint(v), false, false);
    return fmaxf(__uint_as_float(r[0]), __uint_as_float(r[1]));
}
__device__ __forceinline__ float xhalf_sum(float v) {
    uint2v r = __builtin_amdgcn_permlane32_swap(__float_as_uint(v), __float_as_uint(v), false, false);
    return __uint_as_float(r[0]) + __uint_as_float(r[1]);
}

// =====================================================================
// prep: convert mem shards to f16 row-major + f16 transposed, once.
// 32 blocks: (sid, m-half).
// =====================================================================
__global__ void __launch_bounds__(1024)
prep_kernel(const float* __restrict__ memG, unsigned short* __restrict__ mem16,
            unsigned short* __restrict__ memT16)
{
    const int sid = blockIdx.x >> 1, half = blockIdx.x & 1;
    const size_t base = (size_t)sid * (MM*WW);
    for (int i = 0; i < 16; ++i) {
        int idx = half*16384 + i*1024 + threadIdx.x;   // 0..32767 within shard
        float f = memG[base + idx];
        unsigned short h = (unsigned short)(pk2(f, f) & 0xFFFFu);
        mem16[base + idx] = h;
        int m = idx >> 6, w = idx & 63;
        memT16[base + (size_t)w*MM + m] = h;
    }
}

// =====================================================================
// kernel1: user-emb + pe + qpe + Wq staging + phase Q; writes bqf to ws.
// Identical math to the monolith up to (and including) the bqf build.
// =====================================================================
__global__ void __launch_bounds__(1024, 4)
attn_k1(const float* __restrict__ x, const int* __restrict__ user_id,
        const float* __restrict__ uet, const float* __restrict__ W_proc,
        const float* __restrict__ b_proc, const float* __restrict__ Wq,
        unsigned int* __restrict__ qg)
{
    extern __shared__ char smraw[];
    unsigned int*   smw   = (unsigned int*)smraw;
    uint4*          sm128 = (uint4*)smraw;
    float*          smf   = (float*)(smraw + F32_OFF);

    const int t = threadIdx.x;
    const int b = blockIdx.x;
    const int lane = t & 63, wv = t >> 6;        // 16 waves
    const int n16 = lane & 15, quad = lane >> 4;
    const int l31 = lane & 31, hh = lane >> 5;
    const int r = wv & 3, sq = wv >> 2;          // sq 0..3
    const int s0 = sq * 32;

    const int uid = user_id[b];
    const int sid = uid & 15;
    const float* wqX  = Wq + (size_t)sid * KD * RW;

    if (t < EE) smf[UE_O + t] = uet[(size_t)uid*EE + t];

    // ---- Prologue A: Wq x-part (k<256, n<256) -> LDS f16 image [k/8][n][k%8] ----
    for (int i = 0; i < 32; ++i) {
        int idx = i*1024 + t;                    // 0..32767
        int n = idx & 255, kp = idx >> 8;        // kp = k/2
        float w0 = wqX[(size_t)(2*kp)    *RW + n];
        float w1 = wqX[(size_t)(2*kp + 1)*RW + n];
        smw[((((kp>>2)*256 + n) << 2) | (kp & 3))] = pk2(w0, w1);
    }
    __syncthreads();

    // pe
    if (t < PD) {
        float a = b_proc[t];
        #pragma unroll
        for (int e = 0; e < EE; ++e) a = fmaf(smf[UE_O + e], W_proc[e*PD + t], a);
        smf[PE_O + t] = a;
    }
    __syncthreads();
    // qpe partials
    {
        int n = t & 255, h = t >> 8;
        float s = 0.f;
        const float* wr = wqX + (size_t)(256 + h*32)*RW + n;
        #pragma unroll 8
        for (int k = 0; k < 32; ++k) s = fmaf(smf[PE_O + h*32 + k], wr[(size_t)k*RW], s);
        smf[QP_O + h*256 + n] = s;
    }
    __syncthreads();
    if (t < 256) smf[QPE_O + t] = LOG2E * (smf[QP_O + t] + smf[QP_O + 256 + t]
                                         + smf[QP_O + 512 + t] + smf[QP_O + 768 + t]);
    __syncthreads();

    // ---- Phase Q (x-part k<256 only; pe via qpe bias; kc MUST stop at 8) ----
    float4v qacc[4][2];
    #pragma unroll
    for (int mt = 0; mt < 4; ++mt)
        #pragma unroll
        for (int nt = 0; nt < 2; ++nt) qacc[mt][nt] = (float4v)0.f;

    const float* xB = x + (size_t)(b*SSEQ + s0) * INPUT;
    for (int kc = 0; kc < 8; ++kc) {
        H8 afr[4];
        #pragma unroll
        for (int mt = 0; mt < 4; ++mt)
            afr[mt].u4 = sm128[(kc*4 + quad)*256 + r*64 + mt*16 + n16];
        H8 bfr[2];
        #pragma unroll
        for (int nt = 0; nt < 2; ++nt) {
            const float* xg = xB + (size_t)(nt*16 + n16)*INPUT + kc*32 + quad*8;
            float4 a0 = *(const float4*)xg;
            float4 a1 = *(const float4*)(xg + 4);
            bfr[nt].u[0] = pk2(a0.x*LOG2E, a0.y*LOG2E);
            bfr[nt].u[1] = pk2(a0.z*LOG2E, a0.w*LOG2E);
            bfr[nt].u[2] = pk2(a1.x*LOG2E, a1.y*LOG2E);
            bfr[nt].u[3] = pk2(a1.z*LOG2E, a1.w*LOG2E);
        }
        __builtin_amdgcn_s_setprio(1);
        #pragma unroll
        for (int mt = 0; mt < 4; ++mt)
            #pragma unroll
            for (int nt = 0; nt < 2; ++nt)
                qacc[mt][nt] = __builtin_amdgcn_mfma_f32_16x16x32_f16(afr[mt].h8, bfr[nt].h8, qacc[mt][nt], 0, 0, 0);
        __builtin_amdgcn_s_setprio(0);
    }
    #pragma unroll
    for (int mt = 0; mt < 4; ++mt)
        #pragma unroll
        for (int reg = 0; reg < 4; ++reg) {
            float qv = smf[QPE_O + r*64 + mt*16 + quad*4 + reg];
            #pragma unroll
            for (int nt = 0; nt < 2; ++nt) qacc[mt][nt][reg] += qv;
        }
    unsigned int pkq[4][2][2];
    #pragma unroll
    for (int mt = 0; mt < 4; ++mt)
        #pragma unroll
        for (int nt = 0; nt < 2; ++nt) {
            pkq[mt][nt][0] = pk2(qacc[mt][nt][0], qacc[mt][nt][1]);
            pkq[mt][nt][1] = pk2(qacc[mt][nt][2], qacc[mt][nt][3]);
        }
    // ---- repack q into 32x32x16 B-operand layout ----
    H8 bqf[4];
    {
        const int ntSel = (lane >> 4) & 1;           // = bit4 of s5
        const int srcBase = (lane & 15) + (lane & 32);
        #pragma unroll
        for (int kc = 0; kc < 4; ++kc)
            #pragma unroll
            for (int jp = 0; jp < 4; ++jp) {
                const int src = srcBase + ((jp >> 1) << 4);
                int v0 = __shfl((int)pkq[kc][0][jp & 1], src, 64);
                int v1 = __shfl((int)pkq[kc][1][jp & 1], src, 64);
                bqf[kc].u[jp] = (unsigned int)(ntSel ? v1 : v0);
            }
    }
    // ---- store bqf to workspace (u32 pass-through, bit-exact) ----
    #pragma unroll
    for (int kc = 0; kc < 4; ++kc)
        #pragma unroll
        for (int jp = 0; jp < 4; ++jp)
            qg[QIDX(b, r, kc, jp, hh, s0 + l31)] = bqf[kc].u[jp];
}

// =====================================================================
// kernel2: mem-image LDS fill (from prebuilt f16 globals) + flash + tail.
// Flash body identical to R3's.
// =====================================================================
__global__ void __launch_bounds__(1024, 4)
attn_k2(const int* __restrict__ user_id, const unsigned short* __restrict__ mem16,
        const unsigned short* __restrict__ memT16, const unsigned int* __restrict__ qg,
        float* __restrict__ out)
{
    extern __shared__ char smraw[];
    uint4* sm128 = (uint4*)smraw;

    const int t = threadIdx.x;
    const int b = blockIdx.x;
    const int lane = t & 63, wv = t >> 6;        // 16 waves
    const int l31 = lane & 31, hh = lane >> 5;
    const int r = wv & 3, sq = wv >> 2;          // sq 0..3
    const int s0 = sq * 32;
    const int mswz = l31 & 7;

    const int uid = user_id[b];
    const int sid = uid & 15;
    const size_t mbase = (size_t)sid * (MM*WW);

    // ---- load bqf from workspace ----
    H8 bqf[4];
    #pragma unroll
    for (int kc = 0; kc < 4; ++kc)
        #pragma unroll
        for (int jp = 0; jp < 4; ++jp)
            bqf[kc].u[jp] = qg[QIDX(b, r, kc, jp, hh, s0 + l31)];

    // ---- LDS fill: mem rows + memT rows from prebuilt f16 images ----
    for (int i = 0; i < 4; ++i) {
        int id = t + i*1024;
        int m = id >> 3, cw = id & 7;
        sm128[m*8 + (cw ^ (m & 7))] =
            *(const uint4*)(mem16 + mbase + (size_t)m*64 + cw*8);
    }
    for (int i = 0; i < 4; ++i) {
        int id = t + i*1024;
        int w = id & 63, cm = id >> 6;
        sm128[MEMT16 + w*64 + (cm ^ (w & 7))] =
            *(const uint4*)(memT16 + mbase + (size_t)w*MM + cm*8);
    }
    __syncthreads();

    // ========== single-pass flash loop (R3 body) ==========
    f32x16 Oa0 = (f32x16)0.f, Oa1 = (f32x16)0.f;
    float Ml = -1e30f, llp = 0.f;

    H8 afc[4];
    #pragma unroll
    for (int kc = 0; kc < 4; ++kc)
        afc[kc].u4 = sm128[l31*8 + (((kc<<1) + hh) ^ mswz)];

    for (int mtile = 0; mtile < 16; ++mtile) {
        f32x16 Sa = (f32x16)0.f;
        __builtin_amdgcn_s_setprio(1);
        #pragma unroll
        for (int kc = 0; kc < 4; ++kc)
            Sa = __builtin_amdgcn_mfma_f32_32x32x16_f16(afc[kc].h8, bqf[kc].h8, Sa, 0, 0, 0);
        __builtin_amdgcn_s_setprio(0);
        if (mtile < 15) {
            const int mrow = (mtile+1)*32 + l31;
            #pragma unroll
            for (int kc = 0; kc < 4; ++kc)
                afc[kc].u4 = sm128[mrow*8 + (((kc<<1) + hh) ^ mswz)];
        }
        const int c0 = mtile*4 + hh;
        H8 afP0, afP1, afP2, afP3;
        afP0.u4 = sm128[MEMT16 + l31*64        + ( c0      ^ mswz)];
        afP1.u4 = sm128[MEMT16 + l31*64        + ((c0 + 2) ^ mswz)];
        afP2.u4 = sm128[MEMT16 + (32 + l31)*64 + ( c0      ^ mswz)];
        afP3.u4 = sm128[MEMT16 + (32 + l31)*64 + ((c0 + 2) ^ mswz)];
        float m0 = fmaxf(fmaxf(Sa[0], Sa[1]), Sa[2]);
        float m1 = fmaxf(fmaxf(Sa[3], Sa[4]), Sa[5]);
        float m2 = fmaxf(fmaxf(Sa[6], Sa[7]), Sa[8]);
        float m3 = fmaxf(fmaxf(Sa[9], Sa[10]), Sa[11]);
        float m4 = fmaxf(fmaxf(Sa[12], Sa[13]), Sa[14]);
        float m5 = fmaxf(fmaxf(m0, m1), Sa[15]);
        float m6 = fmaxf(fmaxf(m2, m3), m4);
        float tmx = xhalf_max(fmaxf(m5, m6));
        if (__any(tmx > Ml + 8.0f)) {
            float Mn = fmaxf(Ml, tmx);
            float al = __builtin_amdgcn_exp2f(Ml - Mn);
            Ml = Mn;
            llp *= al;
            #pragma unroll
            for (int g = 0; g < 16; ++g) { Oa0[g] *= al; Oa1[g] *= al; }
        }
        float pv[16];
        #pragma unroll
        for (int g = 0; g < 16; ++g) pv[g] = __builtin_amdgcn_exp2f(Sa[g] - Ml);
        float ts = (((pv[0]+pv[1])+(pv[2]+pv[3])) + ((pv[4]+pv[5])+(pv[6]+pv[7])))
                 + (((pv[8]+pv[9])+(pv[10]+pv[11])) + ((pv[12]+pv[13])+(pv[14]+pv[15])));
        llp += ts;
        uint2v rA0 = __builtin_amdgcn_permlane32_swap(pk2(pv[0],pv[1]),   pk2(pv[4],pv[5]),   false, false);
        uint2v rB0 = __builtin_amdgcn_permlane32_swap(pk2(pv[2],pv[3]),   pk2(pv[6],pv[7]),   false, false);
        uint2v rA1 = __builtin_amdgcn_permlane32_swap(pk2(pv[8],pv[9]),   pk2(pv[12],pv[13]), false, false);
        uint2v rB1 = __builtin_amdgcn_permlane32_swap(pk2(pv[10],pv[11]), pk2(pv[14],pv[15]), false, false);
        H8 bp0; bp0.u[0]=rA0[0]; bp0.u[1]=rB0[0]; bp0.u[2]=rA0[1]; bp0.u[3]=rB0[1];
        H8 bp1; bp1.u[0]=rA1[0]; bp1.u[1]=rB1[0]; bp1.u[2]=rA1[1]; bp1.u[3]=rB1[1];
        __builtin_amdgcn_s_setprio(1);
        Oa0 = __builtin_amdgcn_mfma_f32_32x32x16_f16(afP0.h8, bp0.h8, Oa0, 0, 0, 0);
        Oa0 = __builtin_amdgcn_mfma_f32_32x32x16_f16(afP1.h8, bp1.h8, Oa0, 0, 0, 0);
        Oa1 = __builtin_amdgcn_mfma_f32_32x32x16_f16(afP2.h8, bp0.h8, Oa1, 0, 0, 0);
        Oa1 = __builtin_amdgcn_mfma_f32_32x32x16_f16(afP3.h8, bp1.h8, Oa1, 0, 0, 0);
        __builtin_amdgcn_s_setprio(0);
    }

    float inv = 1.0f / xhalf_sum(llp);

    // ---- store read_words ----
    {
        const int s = s0 + l31;
        float* op = out + ((size_t)(b*SSEQ + s)*4 + r)*WW;
        #pragma unroll
        for (int rq = 0; rq < 4; ++rq) {
            float4 o0 = make_float4(Oa0[rq*4+0]*inv, Oa0[rq*4+1]*inv,
                                    Oa0[rq*4+2]*inv, Oa0[rq*4+3]*inv);
            *(float4*)&op[rq*8 + hh*4] = o0;
            float4 o1 = make_float4(Oa1[rq*4+0]*inv, Oa1[rq*4+1]*inv,
                                    Oa1[rq*4+2]*inv, Oa1[rq*4+3]*inv);
            *(float4*)&op[32 + rq*8 + hh*4] = o1;
        }
    }

    // ---- final_state (b == 255): recompute scores, store normalized wts ----
    if (b == BB - 1) {
        const int s = s0 + l31;
        size_t base = (size_t)OUT1 + ((size_t)(s*4 + r) << 9);
        for (int mtile = 0; mtile < 16; ++mtile) {
            f32x16 Sa = (f32x16)0.f;
            const int mrow = mtile*32 + l31;
            #pragma unroll
            for (int kc = 0; kc < 4; ++kc) {
                H8 af; af.u4 = sm128[mrow*8 + (((kc<<1) + hh) ^ mswz)];
                Sa = __builtin_amdgcn_mfma_f32_32x32x16_f16(af.h8, bqf[kc].h8, Sa, 0, 0, 0);
            }
            #pragma unroll
            for (int rq = 0; rq < 4; ++rq) {
                float4 w4 = make_float4(
                    __builtin_amdgcn_exp2f(Sa[rq*4+0] - Ml) * inv,
                    __builtin_amdgcn_exp2f(Sa[rq*4+1] - Ml) * inv,
                    __builtin_amdgcn_exp2f(Sa[rq*4+2] - Ml) * inv,
                    __builtin_amdgcn_exp2f(Sa[rq*4+3] - Ml) * inv);
                *(float4*)&out[base + mtile*32 + rq*8 + hh*4] = w4;
            }
        }
    }
}

// =====================================================================
// Monolith fallback (R3 kernel, verbatim) — used when ws is too small.
// =====================================================================
__global__ void __launch_bounds__(1024, 4)
attn_kernel_mono(const float* __restrict__ x, const int* __restrict__ user_id,
            const float* __restrict__ uet, const float* __restrict__ W_proc,
            const float* __restrict__ b_proc, const float* __restrict__ Wq,
            const float* __restrict__ memG, float* __restrict__ out)
{
    extern __shared__ char smraw[];
    unsigned short* smemu = (unsigned short*)smraw;
    unsigned int*   smw   = (unsigned int*)smraw;
    uint4*          sm128 = (uint4*)smraw;
    float*          smf   = (float*)(smraw + F32_OFF);

    const int t = threadIdx.x;
    const int b = blockIdx.x;
    const int lane = t & 63, wv = t >> 6;
    const int n16 = lane & 15, quad = lane >> 4;
    const int l31 = lane & 31, hh = lane >> 5;
    const int r = wv & 3, sq = wv >> 2;
    const int s0 = sq * 32;
    const int mswz = l31 & 7;

    const int uid = user_id[b];
    const int sid = uid & 15;
    const float* memB = memG + (size_t)sid * (MM*WW);
    const float* wqX  = Wq + (size_t)sid * KD * RW;

    if (t < EE) smf[UE_O + t] = uet[(size_t)uid*EE + t];

    for (int i = 0; i < 32; ++i) {
        int idx = i*1024 + t;
        int n = idx & 255, kp = idx >> 8;
        float w0 = wqX[(size_t)(2*kp)    *RW + n];
        float w1 = wqX[(size_t)(2*kp + 1)*RW + n];
        smw[((((kp>>2)*256 + n) << 2) | (kp & 3))] = pk2(w0, w1);
    }
    __syncthreads();

    if (t < PD) {
        float a = b_proc[t];
        #pragma unroll
        for (int e = 0; e < EE; ++e) a = fmaf(smf[UE_O + e], W_proc[e*PD + t], a);
        smf[PE_O + t] = a;
    }
    __syncthreads();
    {
        int n = t & 255, h = t >> 8;
        float s = 0.f;
        const float* wr = wqX + (size_t)(256 + h*32)*RW + n;
        #pragma unroll 8
        for (int k = 0; k < 32; ++k) s = fmaf(smf[PE_O + h*32 + k], wr[(size_t)k*RW], s);
        smf[QP_O + h*256 + n] = s;
    }
    __syncthreads();
    if (t < 256) smf[QPE_O + t] = LOG2E * (smf[QP_O + t] + smf[QP_O + 256 + t]
                                         + smf[QP_O + 512 + t] + smf[QP_O + 768 + t]);
    __syncthreads();

    float4v qacc[4][2];
    #pragma unroll
    for (int mt = 0; mt < 4; ++mt)
        #pragma unroll
        for (int nt = 0; nt < 2; ++nt) qacc[mt][nt] = (float4v)0.f;

    const float* xB = x + (size_t)(b*SSEQ + s0) * INPUT;
    for (int kc = 0; kc < 8; ++kc) {
        H8 afr[4];
        #pragma unroll
        for (int mt = 0; mt < 4; ++mt)
            afr[mt].u4 = sm128[(kc*4 + quad)*256 + r*64 + mt*16 + n16];
        H8 bfr[2];
        #pragma unroll
        for (int nt = 0; nt < 2; ++nt) {
            const float* xg = xB + (size_t)(nt*16 + n16)*INPUT + kc*32 + quad*8;
            float4 a0 = *(const float4*)xg;
            float4 a1 = *(const float4*)(xg + 4);
            bfr[nt].u[0] = pk2(a0.x*LOG2E, a0.y*LOG2E);
            bfr[nt].u[1] = pk2(a0.z*LOG2E, a0.w*LOG2E);
            bfr[nt].u[2] = pk2(a1.x*LOG2E, a1.y*LOG2E);
            bfr[nt].u[3] = pk2(a1.z*LOG2E, a1.w*LOG2E);
        }
        __builtin_amdgcn_s_setprio(1);
        #pragma unroll
        for (int mt = 0; mt < 4; ++mt)
            #pragma unroll
            for (int nt = 0; nt < 2; ++nt)
                qacc[mt][nt] = __builtin_amdgcn_mfma_f32_16x16x32_f16(afr[mt].h8, bfr[nt].h8, qacc[mt][nt], 0, 0, 0);
        __builtin_amdgcn_s_setprio(0);
    }
    #pragma unroll
    for (int mt = 0; mt < 4; ++mt)
        #pragma unroll
        for (int reg = 0; reg < 4; ++reg) {
            float qv = smf[QPE_O + r*64 + mt*16 + quad*4 + reg];
            #pragma unroll
            for (int nt = 0; nt < 2; ++nt) qacc[mt][nt][reg] += qv;
        }
    unsigned int pkq[4][2][2];
    #pragma unroll
    for (int mt = 0; mt < 4; ++mt)
        #pragma unroll
        for (int nt = 0; nt < 2; ++nt) {
            pkq[mt][nt][0] = pk2(qacc[mt][nt][0], qacc[mt][nt][1]);
            pkq[mt][nt][1] = pk2(qacc[mt][nt][2], qacc[mt][nt][3]);
        }
    H8 bqf[4];
    {
        const int ntSel = (lane >> 4) & 1;
        const int srcBase = (lane & 15) + (lane & 32);
        #pragma unroll
        for (int kc = 0; kc < 4; ++kc)
            #pragma unroll
            for (int jp = 0; jp < 4; ++jp) {
                const int src = srcBase + ((jp >> 1) << 4);
                int v0 = __shfl((int)pkq[kc][0][jp & 1], src, 64);
                int v1 = __shfl((int)pkq[kc][1][jp & 1], src, 64);
                bqf[kc].u[jp] = (unsigned int)(ntSel ? v1 : v0);
            }
    }
    __syncthreads();

    for (int i = 0; i < 4; ++i) {
        int id = t + i*1024;
        int m = id >> 3, cw = id & 7;
        const float* g = memB + m*64 + cw*8;
        float4 a0 = *(const float4*)g;
        float4 a1 = *(const float4*)(g + 4);
        sm128[m*8 + (cw ^ (m & 7))] =
            make_uint4(pk2(a0.x,a0.y), pk2(a0.z,a0.w), pk2(a1.x,a1.y), pk2(a1.z,a1.w));
    }
    __syncthreads();
    for (int i = 0; i < 4; ++i) {
        int id = t + i*1024;
        int w = id & 63, cm = id >> 6;
        unsigned int uu[4];
        #pragma unroll
        for (int p = 0; p < 4; ++p) {
            int m0 = cm*8 + 2*p, m1 = m0 + 1;
            unsigned short lo = smemu[m0*64 + (((w>>3) ^ (m0&7))<<3) + (w&7)];
            unsigned short hi = smemu[m1*64 + (((w>>3) ^ (m1&7))<<3) + (w&7)];
            uu[p] = (unsigned int)lo | ((unsigned int)hi << 16);
        }
        sm128[MEMT16 + w*64 + (cm ^ (w & 7))] = make_uint4(uu[0],uu[1],uu[2],uu[3]);
    }
    __syncthreads();

    f32x16 Oa0 = (f32x16)0.f, Oa1 = (f32x16)0.f;
    float Ml = -1e30f, llp = 0.f;

    H8 afc[4];
    #pragma unroll
    for (int kc = 0; kc < 4; ++kc)
        afc[kc].u4 = sm128[l31*8 + (((kc<<1) + hh) ^ mswz)];

    for (int mtile = 0; mtile < 16; ++mtile) {
        f32x16 Sa = (f32x16)0.f;
        __builtin_amdgcn_s_setprio(1);
        #pragma unroll
        for (int kc = 0; kc < 4; ++kc)
            Sa = __builtin_amdgcn_mfma_f32_32x32x16_f16(afc[kc].h8, bqf[kc].h8, Sa, 0, 0, 0);
        __builtin_amdgcn_s_setprio(0);
        if (mtile < 15) {
            const int mrow = (mtile+1)*32 + l31;
            #pragma unroll
            for (int kc = 0; kc < 4; ++kc)
                afc[kc].u4 = sm128[mrow*8 + (((kc<<1) + hh) ^ mswz)];
        }
        const int c0 = mtile*4 + hh;
        H8 afP0, afP1, afP2, afP3;
        afP0.u4 = sm128[MEMT16 + l31*64        + ( c0      ^ mswz)];
        afP1.u4 = sm128[MEMT16 + l31*64        + ((c0 + 2) ^ mswz)];
        afP2.u4 = sm128[MEMT16 + (32 + l31)*64 + ( c0      ^ mswz)];
        afP3.u4 = sm128[MEMT16 + (32 + l31)*64 + ((c0 + 2) ^ mswz)];
        float m0 = fmaxf(fmaxf(Sa[0], Sa[1]), Sa[2]);
        float m1 = fmaxf(fmaxf(Sa[3], Sa[4]), Sa[5]);
        float m2 = fmaxf(fmaxf(Sa[6], Sa[7]), Sa[8]);
        float m3 = fmaxf(fmaxf(Sa[9], Sa[10]), Sa[11]);
        float m4 = fmaxf(fmaxf(Sa[12], Sa[13]), Sa[14]);
        float m5 = fmaxf(fmaxf(m0, m1), Sa[15]);
        float m6 = fmaxf(fmaxf(m2, m3), m4);
        float tmx = xhalf_max(fmaxf(m5, m6));
        if (__any(tmx > Ml + 8.0f)) {
            float Mn = fmaxf(Ml, tmx);
            float al = __builtin_amdgcn_exp2f(Ml - Mn);
            Ml = Mn;
            llp *= al;
            #pragma unroll
            for (int g = 0; g < 16; ++g) { Oa0[g] *= al; Oa1[g] *= al; }
        }
        float pv[16];
        #pragma unroll
        for (int g = 0; g < 16; ++g) pv[g] = __builtin_amdgcn_exp2f(Sa[g] - Ml);
        float ts = (((pv[0]+pv[1])+(pv[2]+pv[3])) + ((pv[4]+pv[5])+(pv[6]+pv[7])))
                 + (((pv[8]+pv[9])+(pv[10]+pv[11])) + ((pv[12]+pv[13])+(pv[14]+pv[15])));
        llp += ts;
        uint2v rA0 = __builtin_amdgcn_permlane32_swap(pk2(pv[0],pv[1]),   pk2(pv[4],pv[5]),   false, false);
        uint2v rB0 = __builtin_amdgcn_permlane32_swap(pk2(pv[2],pv[3]),   pk2(pv[6],pv[7]),   false, false);
        uint2v rA1 = __builtin_amdgcn_permlane32_swap(pk2(pv[8],pv[9]),   pk2(pv[12],pv[13]), false, false);
        uint2v rB1 = __builtin_amdgcn_permlane32_swap(pk2(pv[10],pv[11]), pk2(pv[14],pv[15]), false, false);
        H8 bp0; bp0.u[0]=rA0[0]; bp0.u[1]=rB0[0]; bp0.u[2]=rA0[1]; bp0.u[3]=rB0[1];
        H8 bp1; bp1.u[0]=rA1[0]; bp1.u[1]=rB1[0]; bp1.u[2]=rA1[1]; bp1.u[3]=rB1[1];
        __builtin_amdgcn_s_setprio(1);
        Oa0 = __builtin_amdgcn_mfma_f32_32x32x16_f16(afP0.h8, bp0.h8, Oa0, 0, 0, 0);
        Oa0 = __builtin_amdgcn_mfma_f32_32x32x16_f16(afP1.h8, bp1.h8, Oa0, 0, 0, 0);
        Oa1 = __builtin_amdgcn_mfma_f32_32x32x16_f16(afP2.h8, bp0.h8, Oa1, 0, 0, 0);
        Oa1 = __builtin_amdgcn_mfma_f32_32x32x16_f16(afP3.h8, bp1.h8, Oa1, 0, 0, 0);
        __builtin_amdgcn_s_setprio(0);
    }

    float inv = 1.0f / xhalf_sum(llp);

    {
        const int s = s0 + l31;
        float* op = out + ((size_t)(b*SSEQ + s)*4 + r)*WW;
        #pragma unroll
        for (int rq = 0; rq < 4; ++rq) {
            float4 o0 = make_float4(Oa0[rq*4+0]*inv, Oa0[rq*4+1]*inv,
                                    Oa0[rq*4+2]*inv, Oa0[rq*4+3]*inv);
            *(float4*)&op[rq*8 + hh*4] = o0;
            float4 o1 = make_float4(Oa1[rq*4+0]*inv, Oa1[rq*4+1]*inv,
                                    Oa1[rq*4+2]*inv, Oa1[rq*4+3]*inv);
            *(float4*)&op[32 + rq*8 + hh*4] = o1;
        }
    }

    if (b == BB - 1) {
        const int s = s0 + l31;
        size_t base = (size_t)OUT1 + ((size_t)(s*4 + r) << 9);
        for (int mtile = 0; mtile < 16; ++mtile) {
            f32x16 Sa = (f32x16)0.f;
            const int mrow = mtile*32 + l31;
            #pragma unroll
            for (int kc = 0; kc < 4; ++kc) {
                H8 af; af.u4 = sm128[mrow*8 + (((kc<<1) + hh) ^ mswz)];
                Sa = __builtin_amdgcn_mfma_f32_32x32x16_f16(af.h8, bqf[kc].h8, Sa, 0, 0, 0);
            }
            #pragma unroll
            for (int rq = 0; rq < 4; ++rq) {
                float4 w4 = make_float4(
                    __builtin_amdgcn_exp2f(Sa[rq*4+0] - Ml) * inv,
                    __builtin_amdgcn_exp2f(Sa[rq*4+1] - Ml) * inv,
                    __builtin_amdgcn_exp2f(Sa[rq*4+2] - Ml) * inv,
                    __builtin_amdgcn_exp2f(Sa[rq*4+3] - Ml) * inv);
                *(float4*)&out[base + mtile*32 + rq*8 + hh*4] = w4;
            }
        }
    }
}

extern "C" void kernel_launch(void* const* d_in, const int* in_sizes, int n_in,
                              void* d_out, int out_size, void* d_ws, size_t ws_size,
                              hipStream_t stream) {
    const float* x    = (const float*)d_in[0];
    const int*   uid  = (const int*)  d_in[1];
    const float* uet  = (const float*)d_in[2];
    const float* Wp   = (const float*)d_in[3];
    const float* bp   = (const float*)d_in[4];
    const float* Wq   = (const float*)d_in[5];
    const float* mem  = (const float*)d_in[6];
    float* out = (float*)d_out;

    if (ws_size >= WS_NEED && d_ws != nullptr) {
        unsigned int*   qg     = (unsigned int*)((char*)d_ws + QG_OFF);
        unsigned short* mem16  = (unsigned short*)((char*)d_ws + M16_OFF);
        unsigned short* memT16 = (unsigned short*)((char*)d_ws + MT16_OFF);
        (void)hipFuncSetAttribute((const void*)attn_k1,
                                  hipFuncAttributeMaxDynamicSharedMemorySize, LDS_BYTES_K1);
        (void)hipFuncSetAttribute((const void*)attn_k2,
                                  hipFuncAttributeMaxDynamicSharedMemorySize, LDS_BYTES_K2);
        prep_kernel<<<32, 1024, 0, stream>>>(mem, mem16, memT16);
        attn_k1<<<BB, 1024, LDS_BYTES_K1, stream>>>(x, uid, uet, Wp, bp, Wq, qg);
        attn_k2<<<BB, 1024, LDS_BYTES_K2, stream>>>(uid, mem16, memT16, qg, out);
    } else {
        (void)hipFuncSetAttribute((const void*)attn_kernel_mono,
                                  hipFuncAttributeMaxDynamicSharedMemorySize, LDS_BYTES_K1);
        attn_kernel_mono<<<BB, 1024, LDS_BYTES_K1, stream>>>(x, uid, uet, Wp, bp, Wq, mem, out);
    }
}

// Round 5
// 177.400 us; speedup vs baseline: 1.0550x; 1.0550x over previous
//
#include <hip/hip_runtime.h>
#include <math.h>

#define BB 256
#define SSEQ 128
#define INPUT 256
#define PD 128
#define EE 64
#define RW 256
#define MM 512
#define WW 64
#define KD 384          // IN_DIM

typedef _Float16 half8 __attribute__((ext_vector_type(8)));
typedef __fp16 fp16x2 __attribute__((ext_vector_type(2)));
typedef float float4v __attribute__((ext_vector_type(4)));
typedef float f32x16 __attribute__((ext_vector_type(16)));
typedef unsigned int uint2v __attribute__((ext_vector_type(2)));

#define LOG2E 1.44269504088896f
#define OUT1 8388608u

// LDS byte layout.
// Phase A (prologue): [0,128K) = Wq x-part f16 image, chunk c = (k>>3)*256 + n.
// Phase B (flash):    [0,64K)  = mem f16 rows (chunk m*8 + (c^(m&7))),
//                     [64K,128K) = memT f16 (chunk w*64 + (cm^(w&7))).
// [128K, 128K+6K) f32 scratch.
#define MEMT_OFF 65536
#define MEMT16   4096            // MEMT_OFF in uint4 units
#define F32_OFF  131072
#define LDS_BYTES (131072 + 6144)
#define UE_O 0
#define PE_O 64
#define QPE_O 192
#define QP_O 448                  // qpart [1024]

union H8 { half8 h8; unsigned int u[4]; uint4 u4; };

__device__ __forceinline__ unsigned int pk2(float a, float b) {
    union { fp16x2 h; unsigned int u; } p;
    p.h = __builtin_amdgcn_cvt_pkrtz(a, b);
    return p.u;
}

// v_permlane32_swap_b32 via the builtin (NOT inline asm: two "+v" asm operands
// holding the same value can be coalesced into ONE physical VGPR -> self-swap
// garbage. That was R1's absmax=4.6e7 failure.)
// returns r[0] = [a_lo | b_lo], r[1] = [a_hi | b_hi]
__device__ __forceinline__ float xhalf_max(float v) {
    uint2v r = __builtin_amdgcn_permlane32_swap(__float_as_uint(v), __float_as_uint(v), false, false);
    return fmaxf(__uint_as_float(r[0]), __uint_as_float(r[1]));
}
__device__ __forceinline__ float xhalf_sum(float v) {
    uint2v r = __builtin_amdgcn_permlane32_swap(__float_as_uint(v), __float_as_uint(v), false, false);
    return __uint_as_float(r[0]) + __uint_as_float(r[1]);
}

// ---------- single fused kernel: 256 blocks x 1024 threads (16 waves) ----------
// HARD-WON CONSTRAINTS (do not violate):
//  * launch_bounds (1024,4): forcing (1024,8) = 64-reg cap -> spills (R7, 2x slower).
//  * No multi-pass restructure of the flash loop (R8: spills, 4x slower).
//  * NEVER store/read MFMA accumulators (Sa) inside the loop beyond the exp/pack
//    path (R8/R9: forces accs into VGPR quads -> spill -> occupancy 6%).
// Flash loop: 32x32x16 MFMA, swapped-operand layout (s = lane&31, hh = lane>>5),
//  permlane-only cross-lane, defer-max THR=8 (log2 units).
// R5 (this round): mtile PAIRING. R4's split measured flash=53us vs 2.6us MFMA
//  floor with no pipe >26% => per-wave latency-chain bound. Pair iterations:
//  2 independent QK chains, ONE joint max tree/permlane/defer branch per 64 m,
//  32 independent exp2, 2 independent PV chains (alternate Oa0/Oa1).
__global__ void __launch_bounds__(1024, 4)
attn_kernel(const float* __restrict__ x, const int* __restrict__ user_id,
            const float* __restrict__ uet, const float* __restrict__ W_proc,
            const float* __restrict__ b_proc, const float* __restrict__ Wq,
            const float* __restrict__ memG, float* __restrict__ out)
{
    extern __shared__ char smraw[];
    unsigned short* smemu = (unsigned short*)smraw;
    unsigned int*   smw   = (unsigned int*)smraw;
    uint4*          sm128 = (uint4*)smraw;
    float*          smf   = (float*)(smraw + F32_OFF);

    const int t = threadIdx.x;
    const int b = blockIdx.x;
    const int lane = t & 63, wv = t >> 6;        // 16 waves
    const int n16 = lane & 15, quad = lane >> 4;
    const int l31 = lane & 31, hh = lane >> 5;
    const int r = wv & 3, sq = wv >> 2;          // sq 0..3
    const int s0 = sq * 32;
    const int mswz = l31 & 7;

    const int uid = user_id[b];
    const int sid = uid & 15;
    const float* memB = memG + (size_t)sid * (MM*WW);
    const float* wqX  = Wq + (size_t)sid * KD * RW;

    if (t < EE) smf[UE_O + t] = uet[(size_t)uid*EE + t];

    // ---- Prologue A: Wq x-part (k<256, n<256) -> LDS f16 image [k/8][n][k%8] ----
    for (int i = 0; i < 32; ++i) {
        int idx = i*1024 + t;                    // 0..32767
        int n = idx & 255, kp = idx >> 8;        // kp = k/2
        float w0 = wqX[(size_t)(2*kp)    *RW + n];
        float w1 = wqX[(size_t)(2*kp + 1)*RW + n];
        smw[((((kp>>2)*256 + n) << 2) | (kp & 3))] = pk2(w0, w1);
    }
    __syncthreads();

    // pe
    if (t < PD) {
        float a = b_proc[t];
        #pragma unroll
        for (int e = 0; e < EE; ++e) a = fmaf(smf[UE_O + e], W_proc[e*PD + t], a);
        smf[PE_O + t] = a;
    }
    __syncthreads();
    // qpe partials
    {
        int n = t & 255, h = t >> 8;
        float s = 0.f;
        const float* wr = wqX + (size_t)(256 + h*32)*RW + n;
        #pragma unroll 8
        for (int k = 0; k < 32; ++k) s = fmaf(smf[PE_O + h*32 + k], wr[(size_t)k*RW], s);
        smf[QP_O + h*256 + n] = s;
    }
    __syncthreads();
    if (t < 256) smf[QPE_O + t] = LOG2E * (smf[QP_O + t] + smf[QP_O + 256 + t]
                                         + smf[QP_O + 512 + t] + smf[QP_O + 768 + t]);
    __syncthreads();

    // ---- Phase Q (x-part k<256 only; pe via qpe bias; kc MUST stop at 8) ----
    float4v qacc[4][2];
    #pragma unroll
    for (int mt = 0; mt < 4; ++mt)
        #pragma unroll
        for (int nt = 0; nt < 2; ++nt) qacc[mt][nt] = (float4v)0.f;

    const float* xB = x + (size_t)(b*SSEQ + s0) * INPUT;
    for (int kc = 0; kc < 8; ++kc) {
        H8 afr[4];
        #pragma unroll
        for (int mt = 0; mt < 4; ++mt)
            afr[mt].u4 = sm128[(kc*4 + quad)*256 + r*64 + mt*16 + n16];
        H8 bfr[2];
        #pragma unroll
        for (int nt = 0; nt < 2; ++nt) {
            const float* xg = xB + (size_t)(nt*16 + n16)*INPUT + kc*32 + quad*8;
            float4 a0 = *(const float4*)xg;
            float4 a1 = *(const float4*)(xg + 4);
            bfr[nt].u[0] = pk2(a0.x*LOG2E, a0.y*LOG2E);
            bfr[nt].u[1] = pk2(a0.z*LOG2E, a0.w*LOG2E);
            bfr[nt].u[2] = pk2(a1.x*LOG2E, a1.y*LOG2E);
            bfr[nt].u[3] = pk2(a1.z*LOG2E, a1.w*LOG2E);
        }
        __builtin_amdgcn_s_setprio(1);
        #pragma unroll
        for (int mt = 0; mt < 4; ++mt)
            #pragma unroll
            for (int nt = 0; nt < 2; ++nt)
                qacc[mt][nt] = __builtin_amdgcn_mfma_f32_16x16x32_f16(afr[mt].h8, bfr[nt].h8, qacc[mt][nt], 0, 0, 0);
        __builtin_amdgcn_s_setprio(0);
    }
    #pragma unroll
    for (int mt = 0; mt < 4; ++mt)
        #pragma unroll
        for (int reg = 0; reg < 4; ++reg) {
            float qv = smf[QPE_O + r*64 + mt*16 + quad*4 + reg];
            #pragma unroll
            for (int nt = 0; nt < 2; ++nt) qacc[mt][nt][reg] += qv;
        }
    unsigned int pkq[4][2][2];
    #pragma unroll
    for (int mt = 0; mt < 4; ++mt)
        #pragma unroll
        for (int nt = 0; nt < 2; ++nt) {
            pkq[mt][nt][0] = pk2(qacc[mt][nt][0], qacc[mt][nt][1]);
            pkq[mt][nt][1] = pk2(qacc[mt][nt][2], qacc[mt][nt][3]);
        }
    // ---- repack q into 32x32x16 B-operand layout (one-time) ----
    H8 bqf[4];
    {
        const int ntSel = (lane >> 4) & 1;           // = bit4 of s5
        const int srcBase = (lane & 15) + (lane & 32);
        #pragma unroll
        for (int kc = 0; kc < 4; ++kc)
            #pragma unroll
            for (int jp = 0; jp < 4; ++jp) {
                const int src = srcBase + ((jp >> 1) << 4);
                int v0 = __shfl((int)pkq[kc][0][jp & 1], src, 64);
                int v1 = __shfl((int)pkq[kc][1][jp & 1], src, 64);
                bqf[kc].u[jp] = (unsigned int)(ntSel ? v1 : v0);
            }
    }
    __syncthreads();                             // all waves done reading Wq image

    // ---- Prologue B: overwrite LDS with mem f16 images (convert + transpose) ----
    for (int i = 0; i < 4; ++i) {
        int id = t + i*1024;
        int m = id >> 3, cw = id & 7;
        const float* g = memB + m*64 + cw*8;
        float4 a0 = *(const float4*)g;
        float4 a1 = *(const float4*)(g + 4);
        sm128[m*8 + (cw ^ (m & 7))] =
            make_uint4(pk2(a0.x,a0.y), pk2(a0.z,a0.w), pk2(a1.x,a1.y), pk2(a1.z,a1.w));
    }
    __syncthreads();
    for (int i = 0; i < 4; ++i) {
        int id = t + i*1024;
        int w = id & 63, cm = id >> 6;
        unsigned int uu[4];
        #pragma unroll
        for (int p = 0; p < 4; ++p) {
            int m0 = cm*8 + 2*p, m1 = m0 + 1;
            unsigned short lo = smemu[m0*64 + (((w>>3) ^ (m0&7))<<3) + (w&7)];
            unsigned short hi = smemu[m1*64 + (((w>>3) ^ (m1&7))<<3) + (w&7)];
            uu[p] = (unsigned int)lo | ((unsigned int)hi << 16);
        }
        sm128[MEMT16 + w*64 + (cm ^ (w & 7))] = make_uint4(uu[0],uu[1],uu[2],uu[3]);
    }
    __syncthreads();

    // ========== flash loop: 8 PAIRS of mtiles, joint softmax per pair ==========
    f32x16 Oa0 = (f32x16)0.f, Oa1 = (f32x16)0.f;
    float Ml = -1e30f, llp = 0.f;

    for (int pp = 0; pp < 8; ++pp) {
        const int ma = pp*64 + l31;              // mtile 2pp rows
        const int mb = ma + 32;                  // mtile 2pp+1 rows
        // QK A-frags for both mtiles (8 independent b128 reads)
        H8 afA[4], afB[4];
        #pragma unroll
        for (int kc = 0; kc < 4; ++kc) {
            afA[kc].u4 = sm128[ma*8 + (((kc<<1) + hh) ^ mswz)];
            afB[kc].u4 = sm128[mb*8 + (((kc<<1) + hh) ^ mswz)];
        }
        f32x16 SaA = (f32x16)0.f, SaB = (f32x16)0.f;
        __builtin_amdgcn_s_setprio(1);
        #pragma unroll
        for (int kc = 0; kc < 4; ++kc) {
            SaA = __builtin_amdgcn_mfma_f32_32x32x16_f16(afA[kc].h8, bqf[kc].h8, SaA, 0, 0, 0);
            SaB = __builtin_amdgcn_mfma_f32_32x32x16_f16(afB[kc].h8, bqf[kc].h8, SaB, 0, 0, 0);
        }
        __builtin_amdgcn_s_setprio(0);
        // PV A-frags for both mtiles -- issue BEFORE softmax so the ~120cy LDS
        // latency hides under the max/exp chain.
        const int cA = 8*pp + hh, cB = cA + 4;
        H8 aPa0, aPa1, aPa2, aPa3, aPb0, aPb1, aPb2, aPb3;
        aPa0.u4 = sm128[MEMT16 + l31*64        + ( cA      ^ mswz)];
        aPa1.u4 = sm128[MEMT16 + l31*64        + ((cA + 2) ^ mswz)];
        aPa2.u4 = sm128[MEMT16 + (32 + l31)*64 + ( cA      ^ mswz)];
        aPa3.u4 = sm128[MEMT16 + (32 + l31)*64 + ((cA + 2) ^ mswz)];
        aPb0.u4 = sm128[MEMT16 + l31*64        + ( cB      ^ mswz)];
        aPb1.u4 = sm128[MEMT16 + l31*64        + ((cB + 2) ^ mswz)];
        aPb2.u4 = sm128[MEMT16 + (32 + l31)*64 + ( cB      ^ mswz)];
        aPb3.u4 = sm128[MEMT16 + (32 + l31)*64 + ((cB + 2) ^ mswz)];
        // joint max over both mtiles (one tree, one permlane, one branch / 64 m)
        float a0 = fmaxf(fmaxf(SaA[0], SaA[1]), fmaxf(SaA[2], SaA[3]));
        float a1 = fmaxf(fmaxf(SaA[4], SaA[5]), fmaxf(SaA[6], SaA[7]));
        float a2 = fmaxf(fmaxf(SaA[8], SaA[9]), fmaxf(SaA[10], SaA[11]));
        float a3 = fmaxf(fmaxf(SaA[12], SaA[13]), fmaxf(SaA[14], SaA[15]));
        float b0 = fmaxf(fmaxf(SaB[0], SaB[1]), fmaxf(SaB[2], SaB[3]));
        float b1 = fmaxf(fmaxf(SaB[4], SaB[5]), fmaxf(SaB[6], SaB[7]));
        float b2 = fmaxf(fmaxf(SaB[8], SaB[9]), fmaxf(SaB[10], SaB[11]));
        float b3 = fmaxf(fmaxf(SaB[12], SaB[13]), fmaxf(SaB[14], SaB[15]));
        float tmx = xhalf_max(fmaxf(fmaxf(fmaxf(a0, a1), fmaxf(a2, a3)),
                                    fmaxf(fmaxf(b0, b1), fmaxf(b2, b3))));
        // defer-max (T13): only rescale when running max grows by > 8 (log2).
        // P entries then bounded by 2^8 -- safe in f16; Ml/inv stay consistent
        // (incl. b==255 tail which reuses Ml/inv).
        if (__any(tmx > Ml + 8.0f)) {
            float Mn = fmaxf(Ml, tmx);
            float al = __builtin_amdgcn_exp2f(Ml - Mn);
            Ml = Mn;
            llp *= al;
            #pragma unroll
            for (int g = 0; g < 16; ++g) { Oa0[g] *= al; Oa1[g] *= al; }
        }
        float pvA[16], pvB[16];
        #pragma unroll
        for (int g = 0; g < 16; ++g) {
            pvA[g] = __builtin_amdgcn_exp2f(SaA[g] - Ml);
            pvB[g] = __builtin_amdgcn_exp2f(SaB[g] - Ml);
        }
        float tsA = (((pvA[0]+pvA[1])+(pvA[2]+pvA[3])) + ((pvA[4]+pvA[5])+(pvA[6]+pvA[7])))
                  + (((pvA[8]+pvA[9])+(pvA[10]+pvA[11])) + ((pvA[12]+pvA[13])+(pvA[14]+pvA[15])));
        float tsB = (((pvB[0]+pvB[1])+(pvB[2]+pvB[3])) + ((pvB[4]+pvB[5])+(pvB[6]+pvB[7])))
                  + (((pvB[8]+pvB[9])+(pvB[10]+pvB[11])) + ((pvB[12]+pvB[13])+(pvB[14]+pvB[15])));
        llp += tsA + tsB;
        // P -> PV B-operand: pack pairs + permlane (T12 pattern), both mtiles
        uint2v rA0 = __builtin_amdgcn_permlane32_swap(pk2(pvA[0],pvA[1]),   pk2(pvA[4],pvA[5]),   false, false);
        uint2v rB0 = __builtin_amdgcn_permlane32_swap(pk2(pvA[2],pvA[3]),   pk2(pvA[6],pvA[7]),   false, false);
        uint2v rA1 = __builtin_amdgcn_permlane32_swap(pk2(pvA[8],pvA[9]),   pk2(pvA[12],pvA[13]), false, false);
        uint2v rB1 = __builtin_amdgcn_permlane32_swap(pk2(pvA[10],pvA[11]), pk2(pvA[14],pvA[15]), false, false);
        uint2v sA0 = __builtin_amdgcn_permlane32_swap(pk2(pvB[0],pvB[1]),   pk2(pvB[4],pvB[5]),   false, false);
        uint2v sB0 = __builtin_amdgcn_permlane32_swap(pk2(pvB[2],pvB[3]),   pk2(pvB[6],pvB[7]),   false, false);
        uint2v sA1 = __builtin_amdgcn_permlane32_swap(pk2(pvB[8],pvB[9]),   pk2(pvB[12],pvB[13]), false, false);
        uint2v sB1 = __builtin_amdgcn_permlane32_swap(pk2(pvB[10],pvB[11]), pk2(pvB[14],pvB[15]), false, false);
        H8 bpA0; bpA0.u[0]=rA0[0]; bpA0.u[1]=rB0[0]; bpA0.u[2]=rA0[1]; bpA0.u[3]=rB0[1];
        H8 bpA1; bpA1.u[0]=rA1[0]; bpA1.u[1]=rB1[0]; bpA1.u[2]=rA1[1]; bpA1.u[3]=rB1[1];
        H8 bpB0; bpB0.u[0]=sA0[0]; bpB0.u[1]=sB0[0]; bpB0.u[2]=sA0[1]; bpB0.u[3]=sB0[1];
        H8 bpB1; bpB1.u[0]=sA1[0]; bpB1.u[1]=sB1[0]; bpB1.u[2]=sA1[1]; bpB1.u[3]=sB1[1];
        // PV: 8 MFMA, alternating Oa0/Oa1 -> two independent 4-deep chains
        __builtin_amdgcn_s_setprio(1);
        Oa0 = __builtin_amdgcn_mfma_f32_32x32x16_f16(aPa0.h8, bpA0.h8, Oa0, 0, 0, 0);
        Oa1 = __builtin_amdgcn_mfma_f32_32x32x16_f16(aPa2.h8, bpA0.h8, Oa1, 0, 0, 0);
        Oa0 = __builtin_amdgcn_mfma_f32_32x32x16_f16(aPa1.h8, bpA1.h8, Oa0, 0, 0, 0);
        Oa1 = __builtin_amdgcn_mfma_f32_32x32x16_f16(aPa3.h8, bpA1.h8, Oa1, 0, 0, 0);
        Oa0 = __builtin_amdgcn_mfma_f32_32x32x16_f16(aPb0.h8, bpB0.h8, Oa0, 0, 0, 0);
        Oa1 = __builtin_amdgcn_mfma_f32_32x32x16_f16(aPb2.h8, bpB0.h8, Oa1, 0, 0, 0);
        Oa0 = __builtin_amdgcn_mfma_f32_32x32x16_f16(aPb1.h8, bpB1.h8, Oa0, 0, 0, 0);
        Oa1 = __builtin_amdgcn_mfma_f32_32x32x16_f16(aPb3.h8, bpB1.h8, Oa1, 0, 0, 0);
        __builtin_amdgcn_s_setprio(0);
    }

    // combine the two half-partials of the denominator (lane <-> lane^32)
    float inv = 1.0f / xhalf_sum(llp);

    // ---- store read_words ----
    {
        const int s = s0 + l31;
        float* op = out + ((size_t)(b*SSEQ + s)*4 + r)*WW;
        #pragma unroll
        for (int rq = 0; rq < 4; ++rq) {
            float4 o0 = make_float4(Oa0[rq*4+0]*inv, Oa0[rq*4+1]*inv,
                                    Oa0[rq*4+2]*inv, Oa0[rq*4+3]*inv);
            *(float4*)&op[rq*8 + hh*4] = o0;
            float4 o1 = make_float4(Oa1[rq*4+0]*inv, Oa1[rq*4+1]*inv,
                                    Oa1[rq*4+2]*inv, Oa1[rq*4+3]*inv);
            *(float4*)&op[32 + rq*8 + hh*4] = o1;
        }
    }

    // ---- final_state (b == 255): recompute scores, store normalized wts ----
    if (b == BB - 1) {
        const int s = s0 + l31;
        size_t base = (size_t)OUT1 + ((size_t)(s*4 + r) << 9);
        for (int mtile = 0; mtile < 16; ++mtile) {
            f32x16 Sa = (f32x16)0.f;
            const int mrow = mtile*32 + l31;
            #pragma unroll
            for (int kc = 0; kc < 4; ++kc) {
                H8 af; af.u4 = sm128[mrow*8 + (((kc<<1) + hh) ^ mswz)];
                Sa = __builtin_amdgcn_mfma_f32_32x32x16_f16(af.h8, bqf[kc].h8, Sa, 0, 0, 0);
            }
            #pragma unroll
            for (int rq = 0; rq < 4; ++rq) {
                float4 w4 = make_float4(
                    __builtin_amdgcn_exp2f(Sa[rq*4+0] - Ml) * inv,
                    __builtin_amdgcn_exp2f(Sa[rq*4+1] - Ml) * inv,
                    __builtin_amdgcn_exp2f(Sa[rq*4+2] - Ml) * inv,
                    __builtin_amdgcn_exp2f(Sa[rq*4+3] - Ml) * inv);
                *(float4*)&out[base + mtile*32 + rq*8 + hh*4] = w4;
            }
        }
    }
}

extern "C" void kernel_launch(void* const* d_in, const int* in_sizes, int n_in,
                              void* d_out, int out_size, void* d_ws, size_t ws_size,
                              hipStream_t stream) {
    const float* x    = (const float*)d_in[0];
    const int*   uid  = (const int*)  d_in[1];
    const float* uet  = (const float*)d_in[2];
    const float* Wp   = (const float*)d_in[3];
    const float* bp   = (const float*)d_in[4];
    const float* Wq   = (const float*)d_in[5];
    const float* mem  = (const float*)d_in[6];
    float* out = (float*)d_out;

    (void)hipFuncSetAttribute((const void*)attn_kernel,
                              hipFuncAttributeMaxDynamicSharedMemorySize, LDS_BYTES);
    attn_kernel<<<BB, 1024, LDS_BYTES, stream>>>(x, uid, uet, Wp, bp, Wq, mem, out);
}

// Round 6
// 169.367 us; speedup vs baseline: 1.1051x; 1.0474x over previous
//
#include <hip/hip_runtime.h>
#include <math.h>

#define BB 256
#define SSEQ 128
#define INPUT 256
#define PD 128
#define EE 64
#define RW 256
#define MM 512
#define WW 64
#define KD 384          // IN_DIM

typedef _Float16 half8 __attribute__((ext_vector_type(8)));
typedef __fp16 fp16x2 __attribute__((ext_vector_type(2)));
typedef float float4v __attribute__((ext_vector_type(4)));
typedef float f32x16 __attribute__((ext_vector_type(16)));
typedef unsigned int uint2v __attribute__((ext_vector_type(2)));

#define LOG2E 1.44269504088896f
#define OUT1 8388608u

// LDS byte layout (R6):
//  [0,64K)    mem f16 rows image   (chunk m*8 + (cw^(m&7)))      -- filled FIRST
//  [64K,128K) scratch f32 (prologue) then memT f16 image (flash)
//  [128K,160K) Wq k-chunk DOUBLE BUFFER, 2 x 16KB (32 k-rows x 256 n f16)
// Total 163840 = 160 KiB exactly (HK/AITER attn allocate the same).
#define MEMT16   4096            // memT base in uint4 units (64K/16)
#define F32_OFF  65536
#define BUF16    8192            // Wq dbuf base in uint4 units (128K/16)
#define LDS_BYTES 163840
#define UE_O 0
#define PE_O 64
#define QPE_O 192
#define QP_O 448                  // qpart [1024]

union H8 { half8 h8; unsigned int u[4]; uint4 u4; };

__device__ __forceinline__ unsigned int pk2(float a, float b) {
    union { fp16x2 h; unsigned int u; } p;
    p.h = __builtin_amdgcn_cvt_pkrtz(a, b);
    return p.u;
}

// v_permlane32_swap_b32 via the builtin (NOT inline asm: two "+v" asm operands
// holding the same value can be coalesced into ONE physical VGPR -> self-swap
// garbage. That was R1's absmax=4.6e7 failure.)
// returns r[0] = [a_lo | b_lo], r[1] = [a_hi | b_hi]
__device__ __forceinline__ float xhalf_max(float v) {
    uint2v r = __builtin_amdgcn_permlane32_swap(__float_as_uint(v), __float_as_uint(v), false, false);
    return fmaxf(__uint_as_float(r[0]), __uint_as_float(r[1]));
}
__device__ __forceinline__ float xhalf_sum(float v) {
    uint2v r = __builtin_amdgcn_permlane32_swap(__float_as_uint(v), __float_as_uint(v), false, false);
    return __uint_as_float(r[0]) + __uint_as_float(r[1]);
}

// ---------- single fused kernel: 256 blocks x 1024 threads (16 waves) ----------
// HARD-WON CONSTRAINTS (do not violate):
//  * launch_bounds (1024,4): 4 waves/SIMD -> 128 unified regs/wave. The R3 flash
//    loop uses EXACTLY that (64 arch + ~64 acc). ANY extra live state in the
//    flash loop spills to scratch (R5 here: pairing -> +26MB HBM spill traffic,
//    +7us). Do not add flash ILP/state. (1024,8) needs <=64 regs: impossible.
//  * No multi-pass restructure of the flash loop (old-R8: spills, 4x slower).
//  * Flash loop body below is R3-final: 32x32x16 swapped-operand, permlane-only
//    cross-lane, defer-max THR=8, QK-frag prefetch, setprio around MFMA.
// R6 (this round): PROLOGUE pipelining. Wq staged in 2x16KB k-chunk double
//  buffer under phase Q (overlaps Wq read + x HBM stream + MFMA, was serial);
//  mem f16 image fill hoisted to kernel top (overlaps pe/qpe/phaseQ); stage
//  writes are conflict-free ds_write_b128 (old: 8-way-conflicted b32).
__global__ void __launch_bounds__(1024, 4)
attn_kernel(const float* __restrict__ x, const int* __restrict__ user_id,
            const float* __restrict__ uet, const float* __restrict__ W_proc,
            const float* __restrict__ b_proc, const float* __restrict__ Wq,
            const float* __restrict__ memG, float* __restrict__ out)
{
    extern __shared__ char smraw[];
    unsigned short* smemu = (unsigned short*)smraw;
    uint4*          sm128 = (uint4*)smraw;
    float*          smf   = (float*)(smraw + F32_OFF);

    const int t = threadIdx.x;
    const int b = blockIdx.x;
    const int lane = t & 63, wv = t >> 6;        // 16 waves
    const int n16 = lane & 15, quad = lane >> 4;
    const int l31 = lane & 31, hh = lane >> 5;
    const int r = wv & 3, sq = wv >> 2;          // sq 0..3
    const int s0 = sq * 32;
    const int mswz = l31 & 7;

    const int uid = user_id[b];
    const int sid = uid & 15;
    const float* memB = memG + (size_t)sid * (MM*WW);
    const float* wqX  = Wq + (size_t)sid * KD * RW;

    // ---- mem f16 image fill [0,64K): hoisted to the top, overlaps pe/qpe/Q ----
    for (int i = 0; i < 4; ++i) {
        int id = t + i*1024;
        int m = id >> 3, cw = id & 7;
        const float* g = memB + m*64 + cw*8;
        float4 a0 = *(const float4*)g;
        float4 a1 = *(const float4*)(g + 4);
        sm128[m*8 + (cw ^ (m & 7))] =
            make_uint4(pk2(a0.x,a0.y), pk2(a0.z,a0.w), pk2(a1.x,a1.y), pk2(a1.z,a1.w));
    }
    if (t < EE) smf[UE_O + t] = uet[(size_t)uid*EE + t];
    __syncthreads();

    // pe
    if (t < PD) {
        float a = b_proc[t];
        #pragma unroll
        for (int e = 0; e < EE; ++e) a = fmaf(smf[UE_O + e], W_proc[e*PD + t], a);
        smf[PE_O + t] = a;
    }
    __syncthreads();
    // qpe partials (k = 256..383 part of Wq, straight from global)
    {
        int n = t & 255, h = t >> 8;
        float s = 0.f;
        const float* wr = wqX + (size_t)(256 + h*32)*RW + n;
        #pragma unroll 8
        for (int k = 0; k < 32; ++k) s = fmaf(smf[PE_O + h*32 + k], wr[(size_t)k*RW], s);
        smf[QP_O + h*256 + n] = s;
    }
    __syncthreads();
    if (t < 256) smf[QPE_O + t] = LOG2E * (smf[QP_O + t] + smf[QP_O + 256 + t]
                                         + smf[QP_O + 512 + t] + smf[QP_O + 768 + t]);
    __syncthreads();

    // ---- stage Wq chunk 0 (k 0..31) into buf0: coalesced loads, b128 write ----
    {
        int kq = t >> 8, n = t & 255;            // kq 0..3, n 0..255
        const float* wr = wqX + (size_t)(kq*8)*RW + n;
        float w0 = wr[0*RW], w1 = wr[1*RW], w2 = wr[2*RW], w3 = wr[3*RW];
        float w4 = wr[4*RW], w5 = wr[5*RW], w6 = wr[6*RW], w7 = wr[7*RW];
        sm128[BUF16 + kq*256 + n] =
            make_uint4(pk2(w0,w1), pk2(w2,w3), pk2(w4,w5), pk2(w6,w7));
    }
    __syncthreads();

    // ---- Phase Q, software-pipelined: stage chunk kc+1 while MFMA-ing kc ----
    float4v qacc[4][2];
    #pragma unroll
    for (int mt = 0; mt < 4; ++mt)
        #pragma unroll
        for (int nt = 0; nt < 2; ++nt) qacc[mt][nt] = (float4v)0.f;

    const float* xB = x + (size_t)(b*SSEQ + s0) * INPUT;
    for (int kc = 0; kc < 8; ++kc) {
        // x loads for this kc issued first (latency covered by stage + frag reads)
        float4 xlo[2], xhi[2];
        #pragma unroll
        for (int nt = 0; nt < 2; ++nt) {
            const float* xg = xB + (size_t)(nt*16 + n16)*INPUT + kc*32 + quad*8;
            xlo[nt] = *(const float4*)xg;
            xhi[nt] = *(const float4*)(xg + 4);
        }
        // stage NEXT k-chunk into the other buffer (no race: readers of this
        // buffer finished at the barrier ending iteration kc-1)
        if (kc < 7) {
            int c = kc + 1;
            int kq = t >> 8, n = t & 255;
            const float* wr = wqX + (size_t)(c*32 + kq*8)*RW + n;
            float w0 = wr[0*RW], w1 = wr[1*RW], w2 = wr[2*RW], w3 = wr[3*RW];
            float w4 = wr[4*RW], w5 = wr[5*RW], w6 = wr[6*RW], w7 = wr[7*RW];
            sm128[BUF16 + (c&1)*1024 + kq*256 + n] =
                make_uint4(pk2(w0,w1), pk2(w2,w3), pk2(w4,w5), pk2(w6,w7));
        }
        H8 afr[4];
        #pragma unroll
        for (int mt = 0; mt < 4; ++mt)
            afr[mt].u4 = sm128[BUF16 + (kc&1)*1024 + quad*256 + r*64 + mt*16 + n16];
        H8 bfr[2];
        #pragma unroll
        for (int nt = 0; nt < 2; ++nt) {
            bfr[nt].u[0] = pk2(xlo[nt].x*LOG2E, xlo[nt].y*LOG2E);
            bfr[nt].u[1] = pk2(xlo[nt].z*LOG2E, xlo[nt].w*LOG2E);
            bfr[nt].u[2] = pk2(xhi[nt].x*LOG2E, xhi[nt].y*LOG2E);
            bfr[nt].u[3] = pk2(xhi[nt].z*LOG2E, xhi[nt].w*LOG2E);
        }
        __builtin_amdgcn_s_setprio(1);
        #pragma unroll
        for (int mt = 0; mt < 4; ++mt)
            #pragma unroll
            for (int nt = 0; nt < 2; ++nt)
                qacc[mt][nt] = __builtin_amdgcn_mfma_f32_16x16x32_f16(afr[mt].h8, bfr[nt].h8, qacc[mt][nt], 0, 0, 0);
        __builtin_amdgcn_s_setprio(0);
        __syncthreads();
    }
    #pragma unroll
    for (int mt = 0; mt < 4; ++mt)
        #pragma unroll
        for (int reg = 0; reg < 4; ++reg) {
            float qv = smf[QPE_O + r*64 + mt*16 + quad*4 + reg];
            #pragma unroll
            for (int nt = 0; nt < 2; ++nt) qacc[mt][nt][reg] += qv;
        }
    unsigned int pkq[4][2][2];
    #pragma unroll
    for (int mt = 0; mt < 4; ++mt)
        #pragma unroll
        for (int nt = 0; nt < 2; ++nt) {
            pkq[mt][nt][0] = pk2(qacc[mt][nt][0], qacc[mt][nt][1]);
            pkq[mt][nt][1] = pk2(qacc[mt][nt][2], qacc[mt][nt][3]);
        }
    // ---- repack q into 32x32x16 B-operand layout (one-time) ----
    H8 bqf[4];
    {
        const int ntSel = (lane >> 4) & 1;           // = bit4 of s5
        const int srcBase = (lane & 15) + (lane & 32);
        #pragma unroll
        for (int kc = 0; kc < 4; ++kc)
            #pragma unroll
            for (int jp = 0; jp < 4; ++jp) {
                const int src = srcBase + ((jp >> 1) << 4);
                int v0 = __shfl((int)pkq[kc][0][jp & 1], src, 64);
                int v1 = __shfl((int)pkq[kc][1][jp & 1], src, 64);
                bqf[kc].u[jp] = (unsigned int)(ntSel ? v1 : v0);
            }
    }
    __syncthreads();      // all waves done with QPE scratch before gather overwrites it

    // ---- memT build: u16-gather transpose from the mem image -> [64K,128K) ----
    for (int i = 0; i < 4; ++i) {
        int id = t + i*1024;
        int w = id & 63, cm = id >> 6;
        unsigned int uu[4];
        #pragma unroll
        for (int p = 0; p < 4; ++p) {
            int m0 = cm*8 + 2*p, m1 = m0 + 1;
            unsigned short lo = smemu[m0*64 + (((w>>3) ^ (m0&7))<<3) + (w&7)];
            unsigned short hi = smemu[m1*64 + (((w>>3) ^ (m1&7))<<3) + (w&7)];
            uu[p] = (unsigned int)lo | ((unsigned int)hi << 16);
        }
        sm128[MEMT16 + w*64 + (cm ^ (w & 7))] = make_uint4(uu[0],uu[1],uu[2],uu[3]);
    }
    __syncthreads();

    // ========== single-pass flash loop (R3-final body, verbatim) ==========
    f32x16 Oa0 = (f32x16)0.f, Oa1 = (f32x16)0.f;
    float Ml = -1e30f, llp = 0.f;

    H8 afc[4];
    #pragma unroll
    for (int kc = 0; kc < 4; ++kc)
        afc[kc].u4 = sm128[l31*8 + (((kc<<1) + hh) ^ mswz)];

    for (int mtile = 0; mtile < 16; ++mtile) {
        f32x16 Sa = (f32x16)0.f;
        __builtin_amdgcn_s_setprio(1);
        #pragma unroll
        for (int kc = 0; kc < 4; ++kc)
            Sa = __builtin_amdgcn_mfma_f32_32x32x16_f16(afc[kc].h8, bqf[kc].h8, Sa, 0, 0, 0);
        __builtin_amdgcn_s_setprio(0);
        if (mtile < 15) {
            const int mrow = (mtile+1)*32 + l31;
            #pragma unroll
            for (int kc = 0; kc < 4; ++kc)
                afc[kc].u4 = sm128[mrow*8 + (((kc<<1) + hh) ^ mswz)];
        }
        const int c0 = mtile*4 + hh;
        H8 afP0, afP1, afP2, afP3;
        afP0.u4 = sm128[MEMT16 + l31*64        + ( c0      ^ mswz)];
        afP1.u4 = sm128[MEMT16 + l31*64        + ((c0 + 2) ^ mswz)];
        afP2.u4 = sm128[MEMT16 + (32 + l31)*64 + ( c0      ^ mswz)];
        afP3.u4 = sm128[MEMT16 + (32 + l31)*64 + ((c0 + 2) ^ mswz)];
        float m0 = fmaxf(fmaxf(Sa[0], Sa[1]), Sa[2]);
        float m1 = fmaxf(fmaxf(Sa[3], Sa[4]), Sa[5]);
        float m2 = fmaxf(fmaxf(Sa[6], Sa[7]), Sa[8]);
        float m3 = fmaxf(fmaxf(Sa[9], Sa[10]), Sa[11]);
        float m4 = fmaxf(fmaxf(Sa[12], Sa[13]), Sa[14]);
        float m5 = fmaxf(fmaxf(m0, m1), Sa[15]);
        float m6 = fmaxf(fmaxf(m2, m3), m4);
        float tmx = xhalf_max(fmaxf(m5, m6));
        // defer-max (T13): rescale only when running max grows by > 8 (log2).
        if (__any(tmx > Ml + 8.0f)) {
            float Mn = fmaxf(Ml, tmx);
            float al = __builtin_amdgcn_exp2f(Ml - Mn);
            Ml = Mn;
            llp *= al;
            #pragma unroll
            for (int g = 0; g < 16; ++g) { Oa0[g] *= al; Oa1[g] *= al; }
        }
        float pv[16];
        #pragma unroll
        for (int g = 0; g < 16; ++g) pv[g] = __builtin_amdgcn_exp2f(Sa[g] - Ml);
        float ts = (((pv[0]+pv[1])+(pv[2]+pv[3])) + ((pv[4]+pv[5])+(pv[6]+pv[7])))
                 + (((pv[8]+pv[9])+(pv[10]+pv[11])) + ((pv[12]+pv[13])+(pv[14]+pv[15])));
        llp += ts;
        uint2v rA0 = __builtin_amdgcn_permlane32_swap(pk2(pv[0],pv[1]),   pk2(pv[4],pv[5]),   false, false);
        uint2v rB0 = __builtin_amdgcn_permlane32_swap(pk2(pv[2],pv[3]),   pk2(pv[6],pv[7]),   false, false);
        uint2v rA1 = __builtin_amdgcn_permlane32_swap(pk2(pv[8],pv[9]),   pk2(pv[12],pv[13]), false, false);
        uint2v rB1 = __builtin_amdgcn_permlane32_swap(pk2(pv[10],pv[11]), pk2(pv[14],pv[15]), false, false);
        H8 bp0; bp0.u[0]=rA0[0]; bp0.u[1]=rB0[0]; bp0.u[2]=rA0[1]; bp0.u[3]=rB0[1];
        H8 bp1; bp1.u[0]=rA1[0]; bp1.u[1]=rB1[0]; bp1.u[2]=rA1[1]; bp1.u[3]=rB1[1];
        __builtin_amdgcn_s_setprio(1);
        Oa0 = __builtin_amdgcn_mfma_f32_32x32x16_f16(afP0.h8, bp0.h8, Oa0, 0, 0, 0);
        Oa0 = __builtin_amdgcn_mfma_f32_32x32x16_f16(afP1.h8, bp1.h8, Oa0, 0, 0, 0);
        Oa1 = __builtin_amdgcn_mfma_f32_32x32x16_f16(afP2.h8, bp0.h8, Oa1, 0, 0, 0);
        Oa1 = __builtin_amdgcn_mfma_f32_32x32x16_f16(afP3.h8, bp1.h8, Oa1, 0, 0, 0);
        __builtin_amdgcn_s_setprio(0);
    }

    // combine the two half-partials of the denominator (lane <-> lane^32)
    float inv = 1.0f / xhalf_sum(llp);

    // ---- store read_words ----
    {
        const int s = s0 + l31;
        float* op = out + ((size_t)(b*SSEQ + s)*4 + r)*WW;
        #pragma unroll
        for (int rq = 0; rq < 4; ++rq) {
            float4 o0 = make_float4(Oa0[rq*4+0]*inv, Oa0[rq*4+1]*inv,
                                    Oa0[rq*4+2]*inv, Oa0[rq*4+3]*inv);
            *(float4*)&op[rq*8 + hh*4] = o0;
            float4 o1 = make_float4(Oa1[rq*4+0]*inv, Oa1[rq*4+1]*inv,
                                    Oa1[rq*4+2]*inv, Oa1[rq*4+3]*inv);
            *(float4*)&op[32 + rq*8 + hh*4] = o1;
        }
    }

    // ---- final_state (b == 255): recompute scores, store normalized wts ----
    if (b == BB - 1) {
        const int s = s0 + l31;
        size_t base = (size_t)OUT1 + ((size_t)(s*4 + r) << 9);
        for (int mtile = 0; mtile < 16; ++mtile) {
            f32x16 Sa = (f32x16)0.f;
            const int mrow = mtile*32 + l31;
            #pragma unroll
            for (int kc = 0; kc < 4; ++kc) {
                H8 af; af.u4 = sm128[mrow*8 + (((kc<<1) + hh) ^ mswz)];
                Sa = __builtin_amdgcn_mfma_f32_32x32x16_f16(af.h8, bqf[kc].h8, Sa, 0, 0, 0);
            }
            #pragma unroll
            for (int rq = 0; rq < 4; ++rq) {
                float4 w4 = make_float4(
                    __builtin_amdgcn_exp2f(Sa[rq*4+0] - Ml) * inv,
                    __builtin_amdgcn_exp2f(Sa[rq*4+1] - Ml) * inv,
                    __builtin_amdgcn_exp2f(Sa[rq*4+2] - Ml) * inv,
                    __builtin_amdgcn_exp2f(Sa[rq*4+3] - Ml) * inv);
                *(float4*)&out[base + mtile*32 + rq*8 + hh*4] = w4;
            }
        }
    }
}

extern "C" void kernel_launch(void* const* d_in, const int* in_sizes, int n_in,
                              void* d_out, int out_size, void* d_ws, size_t ws_size,
                              hipStream_t stream) {
    const float* x    = (const float*)d_in[0];
    const int*   uid  = (const int*)  d_in[1];
    const float* uet  = (const float*)d_in[2];
    const float* Wp   = (const float*)d_in[3];
    const float* bp   = (const float*)d_in[4];
    const float* Wq   = (const float*)d_in[5];
    const float* mem  = (const float*)d_in[6];
    float* out = (float*)d_out;

    (void)hipFuncSetAttribute((const void*)attn_kernel,
                              hipFuncAttributeMaxDynamicSharedMemorySize, LDS_BYTES);
    attn_kernel<<<BB, 1024, LDS_BYTES, stream>>>(x, uid, uet, Wp, bp, Wq, mem, out);
}

// Round 7
// 162.747 us; speedup vs baseline: 1.1500x; 1.0407x over previous
//
#include <hip/hip_runtime.h>
#include <math.h>

#define BB 256
#define SSEQ 128
#define INPUT 256
#define PD 128
#define EE 64
#define RW 256
#define MM 512
#define WW 64
#define KD 384          // IN_DIM

typedef _Float16 half8 __attribute__((ext_vector_type(8)));
typedef __fp16 fp16x2 __attribute__((ext_vector_type(2)));
typedef float float4v __attribute__((ext_vector_type(4)));
typedef float f32x16 __attribute__((ext_vector_type(16)));
typedef unsigned int uint2v __attribute__((ext_vector_type(2)));

#define LOG2E 1.44269504088896f
#define OUT1 8388608u

// LDS byte layout (R3 map, restored).
// Phase A (prologue): [0,128K) = Wq x-part f16 image, chunk c = (k>>3)*256 + n.
// Phase B (flash):    [0,64K)  = mem f16 rows (chunk m*8 + (c^(m&7))),
//                     [64K,128K) = memT f16 (chunk w*64 + (cm^(w&7))).
// [128K, 128K+6K) f32 scratch.
#define MEMT16   4096            // memT base in uint4 units (64K/16)
#define F32_OFF  131072
#define LDS_BYTES (131072 + 6144)
#define UE_O 0
#define PE_O 64
#define QPE_O 192
#define QP_O 448                  // qpart [1024]

union H8 { half8 h8; unsigned int u[4]; uint4 u4; };

__device__ __forceinline__ unsigned int pk2(float a, float b) {
    union { fp16x2 h; unsigned int u; } p;
    p.h = __builtin_amdgcn_cvt_pkrtz(a, b);
    return p.u;
}

// v_permlane32_swap_b32 via the builtin (NOT inline asm: two "+v" asm operands
// holding the same value can be coalesced into ONE physical VGPR -> self-swap
// garbage. That was R1's absmax=4.6e7 failure.)
// returns r[0] = [a_lo | b_lo], r[1] = [a_hi | b_hi]
__device__ __forceinline__ float xhalf_max(float v) {
    uint2v r = __builtin_amdgcn_permlane32_swap(__float_as_uint(v), __float_as_uint(v), false, false);
    return fmaxf(__uint_as_float(r[0]), __uint_as_float(r[1]));
}
__device__ __forceinline__ float xhalf_sum(float v) {
    uint2v r = __builtin_amdgcn_permlane32_swap(__float_as_uint(v), __float_as_uint(v), false, false);
    return __uint_as_float(r[0]) + __uint_as_float(r[1]);
}

// ---------- single fused kernel: 256 blocks x 1024 threads (16 waves) ----------
// HARD-WON CONSTRAINTS (do not violate):
//  * launch_bounds (1024,4): 4 waves/SIMD -> 128 unified regs/wave. The R3 flash
//    loop uses EXACTLY that (64 arch + ~64 acc). ANY extra live state in the
//    flash loop spills to scratch (R5: mtile pairing -> +26MB spill traffic).
//    (1024,8) needs <=64 regs: impossible for this algorithm.
//  * NO barriers inside phase Q or the flash loop (R6: 8 per-kc barriers in a
//    dbuf prologue -> +8.5us. Waves must drift freely over the HBM streams).
//  * No multi-pass restructure of the flash loop (old-R8: spills, 4x slower).
//  * Flash body: 32x32x16 swapped-operand, permlane-only cross-lane, defer-max
//    THR=8, QK-frag prefetch, setprio around MFMA clusters (R3-final).
// R7 (this round): wave DESYNC. All 16 waves run identical code from a common
//  barrier -> 4 waves/SIMD burst-contend each pipe phase-locked, then stall
//  together (no pipe >27% yet 5x above pipe bound). Online softmax is
//  tile-order-invariant, so: per-sq mtile rotation (start = sq*4) + one-time
//  s_sleep stagger keyed on sq (co-resident waves share wv&3, differ in sq).
//  Plus: Prologue-A staging unrolled x4 (8 loads in flight, was 2) and qpe
//  split into 4 accumulator chains (loads hoistable, was 32-deep serial fmaf).
__global__ void __launch_bounds__(1024, 4)
attn_kernel(const float* __restrict__ x, const int* __restrict__ user_id,
            const float* __restrict__ uet, const float* __restrict__ W_proc,
            const float* __restrict__ b_proc, const float* __restrict__ Wq,
            const float* __restrict__ memG, float* __restrict__ out)
{
    extern __shared__ char smraw[];
    unsigned short* smemu = (unsigned short*)smraw;
    unsigned int*   smw   = (unsigned int*)smraw;
    uint4*          sm128 = (uint4*)smraw;
    float*          smf   = (float*)(smraw + F32_OFF);

    const int t = threadIdx.x;
    const int b = blockIdx.x;
    const int lane = t & 63, wv = t >> 6;        // 16 waves
    const int n16 = lane & 15, quad = lane >> 4;
    const int l31 = lane & 31, hh = lane >> 5;
    const int r = wv & 3, sq = wv >> 2;          // sq 0..3
    const int s0 = sq * 32;
    const int mswz = l31 & 7;

    const int uid = user_id[b];
    const int sid = uid & 15;
    const float* memB = memG + (size_t)sid * (MM*WW);
    const float* wqX  = Wq + (size_t)sid * KD * RW;

    if (t < EE) smf[UE_O + t] = uet[(size_t)uid*EE + t];

    // ---- Prologue A: Wq x-part -> LDS f16 image [k/8][n][k%8], unrolled x4 ----
    {
        const int n = t & 255, h = t >> 8;       // n fixed per thread
        for (int i = 0; i < 32; i += 4) {
            float w[8];
            #pragma unroll
            for (int j = 0; j < 4; ++j) {
                int kp = (i + j)*4 + h;
                w[2*j]   = wqX[(size_t)(2*kp)    *RW + n];
                w[2*j+1] = wqX[(size_t)(2*kp + 1)*RW + n];
            }
            #pragma unroll
            for (int j = 0; j < 4; ++j) {
                int kp = (i + j)*4 + h;
                smw[((((kp>>2)*256 + n) << 2) | (kp & 3))] = pk2(w[2*j], w[2*j+1]);
            }
        }
    }
    __syncthreads();

    // pe
    if (t < PD) {
        float a = b_proc[t];
        #pragma unroll
        for (int e = 0; e < EE; ++e) a = fmaf(smf[UE_O + e], W_proc[e*PD + t], a);
        smf[PE_O + t] = a;
    }
    __syncthreads();
    // qpe partials: 4 independent chains so the 32 loads can hoist
    {
        int n = t & 255, h = t >> 8;
        const float* wr = wqX + (size_t)(256 + h*32)*RW + n;
        float sa = 0.f, sb = 0.f, sc = 0.f, sd = 0.f;
        #pragma unroll
        for (int k = 0; k < 32; k += 4) {
            sa = fmaf(smf[PE_O + h*32 + k],     wr[(size_t)(k)*RW],     sa);
            sb = fmaf(smf[PE_O + h*32 + k + 1], wr[(size_t)(k + 1)*RW], sb);
            sc = fmaf(smf[PE_O + h*32 + k + 2], wr[(size_t)(k + 2)*RW], sc);
            sd = fmaf(smf[PE_O + h*32 + k + 3], wr[(size_t)(k + 3)*RW], sd);
        }
        smf[QP_O + h*256 + n] = (sa + sb) + (sc + sd);
    }
    __syncthreads();
    if (t < 256) smf[QPE_O + t] = LOG2E * (smf[QP_O + t] + smf[QP_O + 256 + t]
                                         + smf[QP_O + 512 + t] + smf[QP_O + 768 + t]);
    __syncthreads();

    // ---- Phase Q (x-part k<256 only; pe via qpe bias; kc MUST stop at 8) ----
    float4v qacc[4][2];
    #pragma unroll
    for (int mt = 0; mt < 4; ++mt)
        #pragma unroll
        for (int nt = 0; nt < 2; ++nt) qacc[mt][nt] = (float4v)0.f;

    const float* xB = x + (size_t)(b*SSEQ + s0) * INPUT;
    for (int kc = 0; kc < 8; ++kc) {
        H8 afr[4];
        #pragma unroll
        for (int mt = 0; mt < 4; ++mt)
            afr[mt].u4 = sm128[(kc*4 + quad)*256 + r*64 + mt*16 + n16];
        H8 bfr[2];
        #pragma unroll
        for (int nt = 0; nt < 2; ++nt) {
            const float* xg = xB + (size_t)(nt*16 + n16)*INPUT + kc*32 + quad*8;
            float4 a0 = *(const float4*)xg;
            float4 a1 = *(const float4*)(xg + 4);
            bfr[nt].u[0] = pk2(a0.x*LOG2E, a0.y*LOG2E);
            bfr[nt].u[1] = pk2(a0.z*LOG2E, a0.w*LOG2E);
            bfr[nt].u[2] = pk2(a1.x*LOG2E, a1.y*LOG2E);
            bfr[nt].u[3] = pk2(a1.z*LOG2E, a1.w*LOG2E);
        }
        __builtin_amdgcn_s_setprio(1);
        #pragma unroll
        for (int mt = 0; mt < 4; ++mt)
            #pragma unroll
            for (int nt = 0; nt < 2; ++nt)
                qacc[mt][nt] = __builtin_amdgcn_mfma_f32_16x16x32_f16(afr[mt].h8, bfr[nt].h8, qacc[mt][nt], 0, 0, 0);
        __builtin_amdgcn_s_setprio(0);
    }
    #pragma unroll
    for (int mt = 0; mt < 4; ++mt)
        #pragma unroll
        for (int reg = 0; reg < 4; ++reg) {
            float qv = smf[QPE_O + r*64 + mt*16 + quad*4 + reg];
            #pragma unroll
            for (int nt = 0; nt < 2; ++nt) qacc[mt][nt][reg] += qv;
        }
    unsigned int pkq[4][2][2];
    #pragma unroll
    for (int mt = 0; mt < 4; ++mt)
        #pragma unroll
        for (int nt = 0; nt < 2; ++nt) {
            pkq[mt][nt][0] = pk2(qacc[mt][nt][0], qacc[mt][nt][1]);
            pkq[mt][nt][1] = pk2(qacc[mt][nt][2], qacc[mt][nt][3]);
        }
    // ---- repack q into 32x32x16 B-operand layout (one-time) ----
    H8 bqf[4];
    {
        const int ntSel = (lane >> 4) & 1;           // = bit4 of s5
        const int srcBase = (lane & 15) + (lane & 32);
        #pragma unroll
        for (int kc = 0; kc < 4; ++kc)
            #pragma unroll
            for (int jp = 0; jp < 4; ++jp) {
                const int src = srcBase + ((jp >> 1) << 4);
                int v0 = __shfl((int)pkq[kc][0][jp & 1], src, 64);
                int v1 = __shfl((int)pkq[kc][1][jp & 1], src, 64);
                bqf[kc].u[jp] = (unsigned int)(ntSel ? v1 : v0);
            }
    }
    __syncthreads();                             // all waves done reading Wq image

    // ---- Prologue B: overwrite LDS with mem f16 images (convert + transpose) ----
    for (int i = 0; i < 4; ++i) {
        int id = t + i*1024;
        int m = id >> 3, cw = id & 7;
        const float* g = memB + m*64 + cw*8;
        float4 a0 = *(const float4*)g;
        float4 a1 = *(const float4*)(g + 4);
        sm128[m*8 + (cw ^ (m & 7))] =
            make_uint4(pk2(a0.x,a0.y), pk2(a0.z,a0.w), pk2(a1.x,a1.y), pk2(a1.z,a1.w));
    }
    __syncthreads();
    for (int i = 0; i < 4; ++i) {
        int id = t + i*1024;
        int w = id & 63, cm = id >> 6;
        unsigned int uu[4];
        #pragma unroll
        for (int p = 0; p < 4; ++p) {
            int m0 = cm*8 + 2*p, m1 = m0 + 1;
            unsigned short lo = smemu[m0*64 + (((w>>3) ^ (m0&7))<<3) + (w&7)];
            unsigned short hi = smemu[m1*64 + (((w>>3) ^ (m1&7))<<3) + (w&7)];
            uu[p] = (unsigned int)lo | ((unsigned int)hi << 16);
        }
        sm128[MEMT16 + w*64 + (cm ^ (w & 7))] = make_uint4(uu[0],uu[1],uu[2],uu[3]);
    }
    __syncthreads();

    // ========== single-pass flash loop: rotated + staggered per sq ==========
    // Online softmax is tile-order-invariant: each sq-group starts at mtile
    // sq*4 and wraps. Co-resident waves on a SIMD (same wv&3, sq=0..3) are
    // additionally offset by a one-time s_sleep so their phases interleave.
    if (sq == 1) __builtin_amdgcn_s_sleep(2);
    else if (sq == 2) __builtin_amdgcn_s_sleep(4);
    else if (sq == 3) __builtin_amdgcn_s_sleep(6);

    f32x16 Oa0 = (f32x16)0.f, Oa1 = (f32x16)0.f;
    float Ml = -1e30f, llp = 0.f;
    const int mt0 = sq * 4;

    H8 afc[4];
    #pragma unroll
    for (int kc = 0; kc < 4; ++kc)
        afc[kc].u4 = sm128[(mt0*32 + l31)*8 + (((kc<<1) + hh) ^ mswz)];

    for (int i = 0; i < 16; ++i) {
        const int mtile = (i + mt0) & 15;
        f32x16 Sa = (f32x16)0.f;
        __builtin_amdgcn_s_setprio(1);
        #pragma unroll
        for (int kc = 0; kc < 4; ++kc)
            Sa = __builtin_amdgcn_mfma_f32_32x32x16_f16(afc[kc].h8, bqf[kc].h8, Sa, 0, 0, 0);
        __builtin_amdgcn_s_setprio(0);
        if (i < 15) {
            const int mrow = ((i + 1 + mt0) & 15)*32 + l31;
            #pragma unroll
            for (int kc = 0; kc < 4; ++kc)
                afc[kc].u4 = sm128[mrow*8 + (((kc<<1) + hh) ^ mswz)];
        }
        const int c0 = mtile*4 + hh;
        H8 afP0, afP1, afP2, afP3;
        afP0.u4 = sm128[MEMT16 + l31*64        + ( c0      ^ mswz)];
        afP1.u4 = sm128[MEMT16 + l31*64        + ((c0 + 2) ^ mswz)];
        afP2.u4 = sm128[MEMT16 + (32 + l31)*64 + ( c0      ^ mswz)];
        afP3.u4 = sm128[MEMT16 + (32 + l31)*64 + ((c0 + 2) ^ mswz)];
        float m0 = fmaxf(fmaxf(Sa[0], Sa[1]), Sa[2]);
        float m1 = fmaxf(fmaxf(Sa[3], Sa[4]), Sa[5]);
        float m2 = fmaxf(fmaxf(Sa[6], Sa[7]), Sa[8]);
        float m3 = fmaxf(fmaxf(Sa[9], Sa[10]), Sa[11]);
        float m4 = fmaxf(fmaxf(Sa[12], Sa[13]), Sa[14]);
        float m5 = fmaxf(fmaxf(m0, m1), Sa[15]);
        float m6 = fmaxf(fmaxf(m2, m3), m4);
        float tmx = xhalf_max(fmaxf(m5, m6));
        // defer-max (T13): rescale only when running max grows by > 8 (log2).
        if (__any(tmx > Ml + 8.0f)) {
            float Mn = fmaxf(Ml, tmx);
            float al = __builtin_amdgcn_exp2f(Ml - Mn);
            Ml = Mn;
            llp *= al;
            #pragma unroll
            for (int g = 0; g < 16; ++g) { Oa0[g] *= al; Oa1[g] *= al; }
        }
        float pv[16];
        #pragma unroll
        for (int g = 0; g < 16; ++g) pv[g] = __builtin_amdgcn_exp2f(Sa[g] - Ml);
        float ts = (((pv[0]+pv[1])+(pv[2]+pv[3])) + ((pv[4]+pv[5])+(pv[6]+pv[7])))
                 + (((pv[8]+pv[9])+(pv[10]+pv[11])) + ((pv[12]+pv[13])+(pv[14]+pv[15])));
        llp += ts;
        uint2v rA0 = __builtin_amdgcn_permlane32_swap(pk2(pv[0],pv[1]),   pk2(pv[4],pv[5]),   false, false);
        uint2v rB0 = __builtin_amdgcn_permlane32_swap(pk2(pv[2],pv[3]),   pk2(pv[6],pv[7]),   false, false);
        uint2v rA1 = __builtin_amdgcn_permlane32_swap(pk2(pv[8],pv[9]),   pk2(pv[12],pv[13]), false, false);
        uint2v rB1 = __builtin_amdgcn_permlane32_swap(pk2(pv[10],pv[11]), pk2(pv[14],pv[15]), false, false);
        H8 bp0; bp0.u[0]=rA0[0]; bp0.u[1]=rB0[0]; bp0.u[2]=rA0[1]; bp0.u[3]=rB0[1];
        H8 bp1; bp1.u[0]=rA1[0]; bp1.u[1]=rB1[0]; bp1.u[2]=rA1[1]; bp1.u[3]=rB1[1];
        __builtin_amdgcn_s_setprio(1);
        Oa0 = __builtin_amdgcn_mfma_f32_32x32x16_f16(afP0.h8, bp0.h8, Oa0, 0, 0, 0);
        Oa0 = __builtin_amdgcn_mfma_f32_32x32x16_f16(afP1.h8, bp1.h8, Oa0, 0, 0, 0);
        Oa1 = __builtin_amdgcn_mfma_f32_32x32x16_f16(afP2.h8, bp0.h8, Oa1, 0, 0, 0);
        Oa1 = __builtin_amdgcn_mfma_f32_32x32x16_f16(afP3.h8, bp1.h8, Oa1, 0, 0, 0);
        __builtin_amdgcn_s_setprio(0);
    }

    // combine the two half-partials of the denominator (lane <-> lane^32)
    float inv = 1.0f / xhalf_sum(llp);

    // ---- store read_words ----
    {
        const int s = s0 + l31;
        float* op = out + ((size_t)(b*SSEQ + s)*4 + r)*WW;
        #pragma unroll
        for (int rq = 0; rq < 4; ++rq) {
            float4 o0 = make_float4(Oa0[rq*4+0]*inv, Oa0[rq*4+1]*inv,
                                    Oa0[rq*4+2]*inv, Oa0[rq*4+3]*inv);
            *(float4*)&op[rq*8 + hh*4] = o0;
            float4 o1 = make_float4(Oa1[rq*4+0]*inv, Oa1[rq*4+1]*inv,
                                    Oa1[rq*4+2]*inv, Oa1[rq*4+3]*inv);
            *(float4*)&op[32 + rq*8 + hh*4] = o1;
        }
    }

    // ---- final_state (b == 255): recompute scores, store normalized wts ----
    if (b == BB - 1) {
        const int s = s0 + l31;
        size_t base = (size_t)OUT1 + ((size_t)(s*4 + r) << 9);
        for (int mtile = 0; mtile < 16; ++mtile) {
            f32x16 Sa = (f32x16)0.f;
            const int mrow = mtile*32 + l31;
            #pragma unroll
            for (int kc = 0; kc < 4; ++kc) {
                H8 af; af.u4 = sm128[mrow*8 + (((kc<<1) + hh) ^ mswz)];
                Sa = __builtin_amdgcn_mfma_f32_32x32x16_f16(af.h8, bqf[kc].h8, Sa, 0, 0, 0);
            }
            #pragma unroll
            for (int rq = 0; rq < 4; ++rq) {
                float4 w4 = make_float4(
                    __builtin_amdgcn_exp2f(Sa[rq*4+0] - Ml) * inv,
                    __builtin_amdgcn_exp2f(Sa[rq*4+1] - Ml) * inv,
                    __builtin_amdgcn_exp2f(Sa[rq*4+2] - Ml) * inv,
                    __builtin_amdgcn_exp2f(Sa[rq*4+3] - Ml) * inv);
                *(float4*)&out[base + mtile*32 + rq*8 + hh*4] = w4;
            }
        }
    }
}

extern "C" void kernel_launch(void* const* d_in, const int* in_sizes, int n_in,
                              void* d_out, int out_size, void* d_ws, size_t ws_size,
                              hipStream_t stream) {
    const float* x    = (const float*)d_in[0];
    const int*   uid  = (const int*)  d_in[1];
    const float* uet  = (const float*)d_in[2];
    const float* Wp   = (const float*)d_in[3];
    const float* bp   = (const float*)d_in[4];
    const float* Wq   = (const float*)d_in[5];
    const float* mem  = (const float*)d_in[6];
    float* out = (float*)d_out;

    (void)hipFuncSetAttribute((const void*)attn_kernel,
                              hipFuncAttributeMaxDynamicSharedMemorySize, LDS_BYTES);
    attn_kernel<<<BB, 1024, LDS_BYTES, stream>>>(x, uid, uet, Wp, bp, Wq, mem, out);
}